// Round 4
// baseline (64.535 us; speedup 1.0000x reference)
//
#include <hip/hip_runtime.h>

// YOLOv2 post-process, single fused kernel + 64B memset.
// score = sigm(obj)*sigm(cls), both factors < 1 => score>=T needs obj>=logit(T)
// AND cls>=logit(T). Obj-prefilter skips ~97.4% of the 80MB cls read at T=0.86.
// All blocks scan+collect; the LAST block (device done-counter) does exact
// top-100 (fine-histogram refine + rank count), decode, NMS, output.
// Rescue path (count<100 or overflow) folds into the last block: exact
// single-block histogram rescan — never taken on this data, kept for correctness.
// Outputs (float32 flat, 700): bboxes[100*4] | scores[100] | labels[100] | keep[100]

#define KTOP    100
#define CAP     4096u
#define LBUF    128
#define SELN    512
#define NQ      250880u        // NANCH/4, grid covers exactly
#define NB      980u           // NQ/256
#define THRF    0.86f          // collect threshold on score
#define PRE_T   1.80f          // sigm(1.80)=0.8581 < 0.86 -> conservative prefilter
#define CONF    0.01f
#define NMS_T   0.5f
#define STRIDEF 32.0f
#define COFF    1000000.0f

typedef unsigned long long u64;

__device__ __forceinline__ float sigm(float x) {
  return __builtin_amdgcn_rcpf(1.0f + __builtin_amdgcn_exp2f(-1.442695040888963f * x));
}
__device__ __forceinline__ float fexp(float x) {
  return __builtin_amdgcn_exp2f(1.442695040888963f * x);
}

// ws layout (bytes):
//   [0..64)     meta: {0:count, 1:done, 2:overflow}
//   [64..)      cbits[CAP]  (score float bits, monotone for positive floats)
//   [16448..)   cidx[CAP]

__global__ void __launch_bounds__(256) k_all(const float* __restrict__ obj,
    const float* __restrict__ cls, const float* __restrict__ reg,
    const float* __restrict__ anch, unsigned* __restrict__ meta,
    unsigned* __restrict__ cbits, unsigned* __restrict__ cidx,
    float* __restrict__ out) {
  __shared__ float lsc[LBUF];
  __shared__ unsigned lid[LBUF];
  __shared__ unsigned lcnt, gbase, islast;
  const int tid = threadIdx.x;
  if (tid == 0) lcnt = 0u;
  __syncthreads();

  // ---- scan phase: obj-prefiltered threshold collect ----
  unsigned q = blockIdx.x * 256u + (unsigned)tid;   // q < NQ (grid exact)
  float4 o4 = ((const float4*)obj)[q];
  float ov[4] = {o4.x, o4.y, o4.z, o4.w};
#pragma unroll
  for (int k = 0; k < 4; ++k) {
    if (ov[k] < PRE_T) continue;                    // sigm(obj)<0.8581 -> score<0.86
    unsigned a = q * 4u + (unsigned)k;
    float so = sigm(ov[k]);
    const float4* cp = (const float4*)(cls + (size_t)a * 20u);
#pragma unroll
    for (int v = 0; v < 5; ++v) {
      float4 c = cp[v];
      float cc[4] = {c.x, c.y, c.z, c.w};
#pragma unroll
      for (int j = 0; j < 4; ++j) {
        if (cc[j] < PRE_T) continue;
        float s = so * sigm(cc[j]);
        if (s >= THRF) {
          unsigned p = atomicAdd(&lcnt, 1u);
          if (p < LBUF) { lsc[p] = s; lid[p] = a * 20u + (unsigned)(v * 4 + j); }
        }
      }
    }
  }
  __syncthreads();
  unsigned n = lcnt > LBUF ? LBUF : lcnt;
  if (tid == 0) {
    if (lcnt > LBUF) atomicOr(&meta[2], 1u);
    gbase = n ? atomicAdd(&meta[0], n) : 0u;
  }
  __syncthreads();
  // publish candidates via device-scope atomics (coherent across XCDs)
  for (unsigned t = (unsigned)tid; t < n; t += 256u) {
    unsigned p = gbase + t;
    if (p < CAP) {
      atomicExch(&cbits[p], __float_as_uint(lsc[t]));
      atomicExch(&cidx[p], lid[t]);
    } else atomicOr(&meta[2], 1u);
  }

  // ---- done signal; last block proceeds to selection ----
  __syncthreads();
  if (tid == 0) {
    __threadfence();
    unsigned old = atomicAdd(&meta[1], 1u);
    islast = (old == NB - 1u) ? 1u : 0u;
  }
  __syncthreads();
  if (!islast) return;

  // ===================== LAST BLOCK ONLY =====================
  __threadfence();
  __shared__ unsigned rhist[4096];            // rescue histogram (16 KiB)
  __shared__ u64 selk[SELN];                  // 4 KiB
  __shared__ unsigned fhist[512];             // 2 KiB
  __shared__ unsigned scnt, bstar_s, nsel_s, rcnt;
  __shared__ float sc[KTOP];
  __shared__ unsigned sid[KTOP];
  __shared__ float bx[KTOP][4], ob[KTOP][4], area[KTOP];
  __shared__ u64 sup[KTOP][2], keepm[2];

  unsigned count = atomicAdd(&meta[0], 0u);
  unsigned ovf   = atomicOr(&meta[2], 0u);
  if (count > CAP) { count = CAP; ovf = 1u; }

  if (count < (unsigned)KTOP || ovf) {
    // ---- rescue: exact one-block histogram rescan (never taken in practice) ----
    for (int i = tid; i < 4096; i += 256) rhist[i] = 0u;
    if (tid == 0) rcnt = 0u;
    __syncthreads();
    for (unsigned qq = (unsigned)tid; qq < NQ; qq += 256u) {
      float4 oo = ((const float4*)obj)[qq];
      float o2[4] = {oo.x, oo.y, oo.z, oo.w};
      for (int k = 0; k < 4; ++k) {
        float so = sigm(o2[k]);
        unsigned a = qq * 4u + (unsigned)k;
        const float4* cp = (const float4*)(cls + (size_t)a * 20u);
        for (int v = 0; v < 5; ++v) {
          float4 c = cp[v];
          float cc[4] = {c.x, c.y, c.z, c.w};
          for (int j = 0; j < 4; ++j) {
            float s = so * sigm(cc[j]);
            atomicAdd(&rhist[__float_as_uint(s) >> 19], 1u);  // s<1 -> bin<2032
          }
        }
      }
    }
    __syncthreads();
    if (tid == 0) {
      unsigned cum = 0; int b = 4095;
      for (; b >= 0; --b) { cum += rhist[b]; if (cum >= (unsigned)KTOP) break; }
      bstar_s = (b < 0) ? 0u : (unsigned)b;
    }
    __syncthreads();
    unsigned rb = bstar_s;
    for (unsigned qq = (unsigned)tid; qq < NQ; qq += 256u) {
      float4 oo = ((const float4*)obj)[qq];
      float o2[4] = {oo.x, oo.y, oo.z, oo.w};
      for (int k = 0; k < 4; ++k) {
        float so = sigm(o2[k]);
        unsigned a = qq * 4u + (unsigned)k;
        const float4* cp = (const float4*)(cls + (size_t)a * 20u);
        for (int v = 0; v < 5; ++v) {
          float4 c = cp[v];
          float cc[4] = {c.x, c.y, c.z, c.w};
          for (int j = 0; j < 4; ++j) {
            float s = so * sigm(cc[j]);
            if ((__float_as_uint(s) >> 19) >= rb) {
              unsigned p = atomicAdd(&rcnt, 1u);
              if (p < CAP) {  // same block consumes: plain stores fine
                cbits[p] = __float_as_uint(s);
                cidx[p]  = a * 20u + (unsigned)(v * 4 + j);
              }
            }
          }
        }
      }
    }
    __syncthreads();
    count = rcnt; if (count > CAP) count = CAP;
  }

  // ---- fine refine: bin=(bits>>14)-64512 exact+monotone on [0.5,1) ----
  for (int i = tid; i < 512; i += 256) fhist[i] = 0u;
  if (tid == 0) scnt = 0u;
  if (tid < KTOP) { sc[tid] = 0.0f; sid[tid] = 0u; sup[tid][0] = 0ull; sup[tid][1] = 0ull; }
  __syncthreads();
  for (unsigned t = (unsigned)tid; t < count; t += 256u) {
    unsigned sb = atomicOr(&cbits[t], 0u);   // coherent read
    int bin = (int)(sb >> 14) - 64512;
    bin = bin < 0 ? 0 : (bin > 511 ? 511 : bin);
    atomicAdd(&fhist[bin], 1u);
  }
  __syncthreads();
  if (tid == 0) {
    unsigned cum = 0; int b = 511;
    for (; b >= 0; --b) { cum += fhist[b]; if (cum >= (unsigned)KTOP) break; }
    bstar_s = (b < 0) ? 0u : (unsigned)b;
    nsel_s  = cum;
  }
  __syncthreads();
  const unsigned bstar = bstar_s;
  const bool small = (nsel_s <= (unsigned)SELN);

  if (small) {  // compact survivors (typical ~110)
    for (unsigned t = (unsigned)tid; t < count; t += 256u) {
      unsigned sb = atomicOr(&cbits[t], 0u);
      unsigned ii = atomicOr(&cidx[t], 0u);
      int bin = (int)(sb >> 14) - 64512;
      bin = bin < 0 ? 0 : (bin > 511 ? 511 : bin);
      if ((unsigned)bin >= bstar) {
        unsigned p = atomicAdd(&scnt, 1u);
        if (p < (unsigned)SELN)
          selk[p] = ((u64)sb << 32) | (u64)(0xFFFFFFFFu - ii);  // idx asc on ties
      }
    }
  }
  __syncthreads();

  if (small) {
    unsigned nn = scnt > (unsigned)SELN ? (unsigned)SELN : scnt;
    for (unsigned t = (unsigned)tid; t < nn; t += 256u) {
      u64 k = selk[t];
      unsigned rank = 0;
      for (unsigned j = 0; j < nn; ++j) rank += (selk[j] > k) ? 1u : 0u;
      if (rank < (unsigned)KTOP) {
        sc[rank]  = __uint_as_float((unsigned)(k >> 32));
        sid[rank] = 0xFFFFFFFFu - (unsigned)(k & 0xFFFFFFFFull);
      }
    }
  } else {  // fallback: exact rank over full global candidate set (never taken)
    for (unsigned t = (unsigned)tid; t < count; t += 256u) {
      unsigned sb = atomicOr(&cbits[t], 0u);
      unsigned ii = atomicOr(&cidx[t], 0u);
      u64 k = ((u64)sb << 32) | (u64)(0xFFFFFFFFu - ii);
      unsigned rank = 0;
      for (unsigned j = 0; j < count; ++j) {
        unsigned sb2 = atomicOr(&cbits[j], 0u);
        unsigned i2  = atomicOr(&cidx[j], 0u);
        u64 k2 = ((u64)sb2 << 32) | (u64)(0xFFFFFFFFu - i2);
        rank += (k2 > k) ? 1u : 0u;
      }
      if (rank < (unsigned)KTOP) {
        sc[rank]  = __uint_as_float((unsigned)(k >> 32));
        sid[rank] = 0xFFFFFFFFu - (unsigned)(k & 0xFFFFFFFFull);
      }
    }
  }
  __syncthreads();

  // ---- decode boxes for top-100 ----
  if (tid < KTOP) {
    unsigned idx = sid[tid];
    unsigned a = idx / 20u, lab = idx % 20u;
    float4 r  = ((const float4*)reg)[a];
    float4 an = ((const float4*)anch)[a];
    float cx = (sigm(r.x) + an.x) * STRIDEF;
    float cy = (sigm(r.y) + an.y) * STRIDEF;
    float w  = fexp(r.z) * an.z;
    float h  = fexp(r.w) * an.w;
    float x1 = cx - 0.5f * w, y1 = cy - 0.5f * h;
    float x2 = cx + 0.5f * w, y2 = cy + 0.5f * h;
    bx[tid][0] = x1; bx[tid][1] = y1; bx[tid][2] = x2; bx[tid][3] = y2;
    float off = (float)lab * COFF;
    float o0 = x1 + off, o1 = y1 + off, o2 = x2 + off, o3 = y2 + off;
    ob[tid][0] = o0; ob[tid][1] = o1; ob[tid][2] = o2; ob[tid][3] = o3;
    area[tid] = (o2 - o0) * (o3 - o1);
  }
  __syncthreads();

  // ---- pairwise suppression mask (j > i only, per reference) ----
  for (int p = tid; p < KTOP * KTOP; p += 256) {
    int i = p / KTOP, j = p % KTOP;
    if (j > i) {
      float xx1 = fmaxf(ob[i][0], ob[j][0]);
      float yy1 = fmaxf(ob[i][1], ob[j][1]);
      float xx2 = fminf(ob[i][2], ob[j][2]);
      float yy2 = fminf(ob[i][3], ob[j][3]);
      float w = fmaxf(1e-10f, xx2 - xx1);
      float h = fmaxf(1e-10f, yy2 - yy1);
      float inter = w * h;
      float iou = inter / (area[i] + area[j] - inter);
      if (iou > NMS_T) atomicOr(&sup[i][j >> 6], 1ull << (j & 63));
    }
  }
  __syncthreads();

  // ---- serial greedy NMS over bitmasks (exactly the reference fori_loop) ----
  if (tid == 0) {
    u64 k0 = 0ull, k1 = 0ull;
    for (int t = 0; t < 64; ++t)    if (sc[t] > CONF) k0 |= (1ull << t);
    for (int t = 64; t < KTOP; ++t) if (sc[t] > CONF) k1 |= (1ull << (t - 64));
    for (int i = 0; i < KTOP; ++i) {
      bool ki = (i < 64) ? ((k0 >> i) & 1ull) : ((k1 >> (i - 64)) & 1ull);
      if (ki) { k0 &= ~sup[i][0]; k1 &= ~sup[i][1]; }
    }
    keepm[0] = k0; keepm[1] = k1;
  }
  __syncthreads();

  if (tid < KTOP) {
    out[tid * 4 + 0] = bx[tid][0];
    out[tid * 4 + 1] = bx[tid][1];
    out[tid * 4 + 2] = bx[tid][2];
    out[tid * 4 + 3] = bx[tid][3];
    out[400 + tid] = sc[tid];
    out[500 + tid] = (float)(sid[tid] % 20u);
    bool kp = (tid < 64) ? ((keepm[0] >> tid) & 1ull)
                         : ((keepm[1] >> (tid - 64)) & 1ull);
    out[600 + tid] = kp ? 1.0f : 0.0f;
  }
}

extern "C" void kernel_launch(void* const* d_in, const int* in_sizes, int n_in,
                              void* d_out, int out_size, void* d_ws, size_t ws_size,
                              hipStream_t stream) {
  (void)in_sizes; (void)n_in; (void)out_size; (void)ws_size;
  const float* obj  = (const float*)d_in[0];
  const float* cls  = (const float*)d_in[1];
  const float* reg  = (const float*)d_in[2];
  const float* anch = (const float*)d_in[3];
  float* out = (float*)d_out;

  unsigned* meta  = (unsigned*)d_ws;
  unsigned* cbits = (unsigned*)((char*)d_ws + 64);
  unsigned* cidx  = (unsigned*)((char*)d_ws + 64 + CAP * 4);

  hipMemsetAsync(meta, 0, 64, stream);
  hipLaunchKernelGGL(k_all, dim3(NB), dim3(256), 0, stream,
                     obj, cls, reg, anch, meta, cbits, cidx, out);
}

// Round 5
// 51.722 us; speedup vs baseline: 1.2477x; 1.2477x over previous
//
#include <hip/hip_runtime.h>

// YOLOv2 post-process, 2 kernels + 64B memset.
// score = sigm(obj)*sigm(cls), both < 1 => score>=T needs obj>=logit(T) AND
// cls>=logit(T). Obj-prefilter skips ~97.4% of the 80MB cls read at T=0.86.
// k_scan: prefiltered collect of packed (score|~idx) u64 candidates (~1100).
// k_tail: 1 block — fhist refine (wave-parallel suffix scan), exact rank,
// decode, ballot-built NMS masks, register/readlane greedy NMS. Kernel
// boundary provides cross-XCD coherence (no fences, no consume atomics).
// Rescue path (count<100/overflow) inside k_tail — never taken, correctness only.
// Outputs (float32 flat, 700): bboxes[400] | scores[100] | labels[100] | keep[100]

#define KTOP    100
#define CAP     4096u
#define LBUF    128
#define SELN    512
#define NQ      250880u        // anchors/4; grid covers exactly
#define NB      980u           // NQ/256
#define THRF    0.86f
#define PRE_T   1.80f          // sigm(1.80)=0.8581 < 0.86 -> conservative prefilter
#define CONF    0.01f
#define NMS_T   0.5f
#define STRIDEF 32.0f
#define COFF    1000000.0f

typedef unsigned long long u64;
typedef unsigned u32;

__device__ __forceinline__ float sigm(float x) {
  return __builtin_amdgcn_rcpf(1.0f + __builtin_amdgcn_exp2f(-1.442695040888963f * x));
}
__device__ __forceinline__ float fexp(float x) {
  return __builtin_amdgcn_exp2f(1.442695040888963f * x);
}

// ws: [0..64) meta {0:count, 1:overflow}; [64..) cand u64[CAP]

__global__ void __launch_bounds__(256) k_scan(const float* __restrict__ obj,
    const float* __restrict__ cls, u32* __restrict__ meta,
    u64* __restrict__ cand) {
  __shared__ u64 lkey[LBUF];
  __shared__ u32 lcnt, gbase;
  const int tid = threadIdx.x;
  if (tid == 0) lcnt = 0u;
  __syncthreads();

  u32 q = blockIdx.x * 256u + (u32)tid;            // q < NQ (grid exact)
  float4 o4 = ((const float4*)obj)[q];
  float ov[4] = {o4.x, o4.y, o4.z, o4.w};
#pragma unroll
  for (int k = 0; k < 4; ++k) {
    if (ov[k] < PRE_T) continue;
    u32 a = q * 4u + (u32)k;
    float so = sigm(ov[k]);
    const float4* cp = (const float4*)(cls + (size_t)a * 20u);
#pragma unroll
    for (int v = 0; v < 5; ++v) {
      float4 c = cp[v];
      float cc[4] = {c.x, c.y, c.z, c.w};
#pragma unroll
      for (int j = 0; j < 4; ++j) {
        if (cc[j] < PRE_T) continue;
        float s = so * sigm(cc[j]);
        if (s >= THRF) {
          u32 p = atomicAdd(&lcnt, 1u);
          u32 idx = a * 20u + (u32)(v * 4 + j);
          if (p < LBUF)
            lkey[p] = ((u64)__float_as_uint(s) << 32) | (u64)(0xFFFFFFFFu - idx);
        }
      }
    }
  }
  __syncthreads();
  u32 n = lcnt > LBUF ? LBUF : lcnt;
  if (tid == 0) {
    if (lcnt > LBUF) atomicOr(&meta[1], 1u);
    gbase = n ? atomicAdd(&meta[0], n) : 0u;
  }
  __syncthreads();
  for (u32 t = (u32)tid; t < n; t += 256u) {
    u32 p = gbase + t;
    if (p < CAP) cand[p] = lkey[t];                // plain store: kernel boundary
    else atomicOr(&meta[1], 1u);                   //  publishes it coherently
  }
}

__global__ void __launch_bounds__(256) k_tail(const float* __restrict__ obj,
    const float* __restrict__ cls, const float* __restrict__ reg,
    const float* __restrict__ anch, u32* __restrict__ meta,
    u64* __restrict__ cand, float* __restrict__ out) {
  __shared__ u32 rhist[2048];
  __shared__ u64 selk[SELN];
  __shared__ u32 fhist[512];
  __shared__ u32 scnt, bstar_s, nsel_s, rcnt;
  __shared__ float sc[KTOP];
  __shared__ u32 sid[KTOP];
  __shared__ float bx[KTOP][4], ob4[KTOP][4], area_s[KTOP];
  __shared__ u64 suplo[KTOP], suphi[KTOP], keepm[2];
  const int tid = threadIdx.x;
  const int lane = tid & 63;

  u32 count = meta[0], ovf = meta[1];
  if (count > CAP) { count = CAP; ovf = 1u; }

  if (count < (u32)KTOP || ovf) {
    // ---- rescue: exact one-block histogram rescan (never taken in practice) ----
    for (int i = tid; i < 2048; i += 256) rhist[i] = 0u;
    if (tid == 0) rcnt = 0u;
    __syncthreads();
    for (u32 qq = (u32)tid; qq < NQ; qq += 256u) {
      float4 oo = ((const float4*)obj)[qq];
      float o2[4] = {oo.x, oo.y, oo.z, oo.w};
      for (int k = 0; k < 4; ++k) {
        float so = sigm(o2[k]);
        u32 a = qq * 4u + (u32)k;
        const float4* cp = (const float4*)(cls + (size_t)a * 20u);
        for (int v = 0; v < 5; ++v) {
          float4 c = cp[v];
          float cc[4] = {c.x, c.y, c.z, c.w};
          for (int j = 0; j < 4; ++j)
            atomicAdd(&rhist[__float_as_uint(so * sigm(cc[j])) >> 19], 1u);
        }
      }
    }
    __syncthreads();
    if (tid == 0) {
      u32 cum = 0; int b = 2047;
      for (; b >= 0; --b) { cum += rhist[b]; if (cum >= (u32)KTOP) break; }
      bstar_s = (b < 0) ? 0u : (u32)b;
    }
    __syncthreads();
    u32 rb = bstar_s;
    for (u32 qq = (u32)tid; qq < NQ; qq += 256u) {
      float4 oo = ((const float4*)obj)[qq];
      float o2[4] = {oo.x, oo.y, oo.z, oo.w};
      for (int k = 0; k < 4; ++k) {
        float so = sigm(o2[k]);
        u32 a = qq * 4u + (u32)k;
        const float4* cp = (const float4*)(cls + (size_t)a * 20u);
        for (int v = 0; v < 5; ++v) {
          float4 c = cp[v];
          float cc[4] = {c.x, c.y, c.z, c.w};
          for (int j = 0; j < 4; ++j) {
            float s = so * sigm(cc[j]);
            if ((__float_as_uint(s) >> 19) >= rb) {
              u32 p = atomicAdd(&rcnt, 1u);
              u32 idx = a * 20u + (u32)(v * 4 + j);
              if (p < CAP)
                cand[p] = ((u64)__float_as_uint(s) << 32) | (u64)(0xFFFFFFFFu - idx);
            }
          }
        }
      }
    }
    __threadfence_block();
    __syncthreads();
    count = rcnt; if (count > CAP) count = CAP;
  }

  // ---- fine histogram: bin=(bits>>14)-64512 exact+monotone on [0.5,1) ----
  for (int i = tid; i < 512; i += 256) fhist[i] = 0u;
  if (tid == 0) scnt = 0u;
  if (tid < KTOP) { sc[tid] = 0.0f; sid[tid] = 0u; }
  __syncthreads();
  for (u32 t = (u32)tid; t < count; t += 256u) {
    int bin = (int)((u32)(cand[t] >> 32) >> 14) - 64512;
    bin = bin < 0 ? 0 : (bin > 511 ? 511 : bin);
    atomicAdd(&fhist[bin], 1u);
  }
  __syncthreads();

  // ---- bstar via wave-0 suffix scan (no serial 512-loop) ----
  if (tid < 64) {
    u32 b[8];
#pragma unroll
    for (int i = 0; i < 8; ++i) b[i] = fhist[lane * 8 + i];
    u32 seg = b[0] + b[1] + b[2] + b[3] + b[4] + b[5] + b[6] + b[7];
    u32 suf = seg;
#pragma unroll
    for (int d = 1; d < 64; d <<= 1) {
      u32 up = __shfl_down(suf, d);
      if (lane + d < 64) suf += up;
    }
    u64 mask = __ballot(suf >= (u32)KTOP);
    if (mask == 0ull) {
      if (lane == 0) { bstar_s = 0u; nsel_s = count; }
    } else {
      int lstar = 63 - __builtin_clzll(mask);
      int src = lstar < 63 ? lstar + 1 : 63;
      u32 cumAbove = __shfl(suf, src);
      if (lstar == 63) cumAbove = 0u;
      if (lane == lstar) {
        u32 c = cumAbove; int found = 0; u32 ns = count; u32 bs = 0u;
#pragma unroll
        for (int i = 7; i >= 0; --i) {
          c += b[i];
          if (!found && c >= (u32)KTOP) { found = 1; bs = (u32)(lane * 8 + i); ns = c; }
        }
        bstar_s = bs; nsel_s = ns;
      }
    }
  }
  __syncthreads();
  const u32 bstar = bstar_s;
  const bool small = (nsel_s <= (u32)SELN);

  // ---- compact survivors (typical ~110) ----
  if (small) {
    for (u32 t = (u32)tid; t < count; t += 256u) {
      u64 k = cand[t];
      int bin = (int)((u32)(k >> 32) >> 14) - 64512;
      bin = bin < 0 ? 0 : (bin > 511 ? 511 : bin);
      if ((u32)bin >= bstar) {
        u32 p = atomicAdd(&scnt, 1u);
        if (p < (u32)SELN) selk[p] = k;
      }
    }
  }
  __syncthreads();

  if (small) {
    u32 nn = scnt > (u32)SELN ? (u32)SELN : scnt;
    for (u32 t = (u32)tid; t < nn; t += 256u) {
      u64 k = selk[t];
      u32 rank = 0;
      for (u32 j = 0; j < nn; ++j) rank += (selk[j] > k) ? 1u : 0u;
      if (rank < (u32)KTOP) {
        sc[rank]  = __uint_as_float((u32)(k >> 32));
        sid[rank] = 0xFFFFFFFFu - (u32)(k & 0xFFFFFFFFull);
      }
    }
  } else {  // pathological fallback: exact rank over full global set (never taken)
    for (u32 t = (u32)tid; t < count; t += 256u) {
      u64 k = cand[t];
      u32 rank = 0;
      for (u32 j = 0; j < count; ++j) rank += (cand[j] > k) ? 1u : 0u;
      if (rank < (u32)KTOP) {
        sc[rank]  = __uint_as_float((u32)(k >> 32));
        sid[rank] = 0xFFFFFFFFu - (u32)(k & 0xFFFFFFFFull);
      }
    }
  }
  __syncthreads();

  // ---- decode top-100 ----
  if (tid < KTOP) {
    u32 idx = sid[tid];
    u32 a = idx / 20u, lab = idx % 20u;
    float4 r  = ((const float4*)reg)[a];
    float4 an = ((const float4*)anch)[a];
    float cx = (sigm(r.x) + an.x) * STRIDEF;
    float cy = (sigm(r.y) + an.y) * STRIDEF;
    float w  = fexp(r.z) * an.z;
    float h  = fexp(r.w) * an.w;
    float x1 = cx - 0.5f * w, y1 = cy - 0.5f * h;
    float x2 = cx + 0.5f * w, y2 = cy + 0.5f * h;
    bx[tid][0] = x1; bx[tid][1] = y1; bx[tid][2] = x2; bx[tid][3] = y2;
    float off = (float)lab * COFF;
    float o0 = x1 + off, o1 = y1 + off, o2 = x2 + off, o3 = y2 + off;
    ob4[tid][0] = o0; ob4[tid][1] = o1; ob4[tid][2] = o2; ob4[tid][3] = o3;
    area_s[tid] = (o2 - o0) * (o3 - o1);
  }
  __syncthreads();

  // ---- sup masks via ballot: waves 0/1, one 64-bit row-half per ballot ----
  if (tid < 128) {
    int w = tid >> 6;                  // 0: cols 0-63, 1: cols 64-99
    int j = w * 64 + lane;
    bool jv = j < KTOP;
    float o0 = jv ? ob4[j][0] : 0.f, o1 = jv ? ob4[j][1] : 0.f;
    float o2 = jv ? ob4[j][2] : 0.f, o3 = jv ? ob4[j][3] : 0.f;
    float aj = jv ? area_s[j] : 0.f;
    for (int i = 0; i < KTOP; ++i) {
      float i0 = ob4[i][0], i1 = ob4[i][1], i2 = ob4[i][2], i3 = ob4[i][3];
      float ai = area_s[i];
      float xx1 = fmaxf(i0, o0), yy1 = fmaxf(i1, o1);
      float xx2 = fminf(i2, o2), yy2 = fminf(i3, o3);
      float ww = fmaxf(1e-10f, xx2 - xx1), hh = fmaxf(1e-10f, yy2 - yy1);
      float inter = ww * hh;
      float iou = inter / (ai + aj - inter);
      u64 m = __ballot(jv && (j > i) && (iou > NMS_T));
      if (lane == 0) { if (w == 0) suplo[i] = m; else suphi[i] = m; }
    }
  }
  __syncthreads();

  // ---- greedy NMS: rows in wave-0 registers, unrolled readlane, uniform ops ----
  if (tid < 64) {
    u64 rAlo = suplo[lane],                rAhi = suphi[lane];                // rows 0-63
    u64 rBlo = lane < 36 ? suplo[64 + lane] : 0ull;
    u64 rBhi = lane < 36 ? suphi[64 + lane] : 0ull;                          // rows 64-99
    u64 k0 = __ballot(sc[lane] > CONF);
    u64 k1 = __ballot(lane < 36 && sc[64 + lane] > CONF);
#pragma unroll
    for (int i = 0; i < 64; ++i) {
      u64 s0 = __shfl(rAlo, i), s1 = __shfl(rAhi, i);
      if ((k0 >> i) & 1ull) { k0 &= ~s0; k1 &= ~s1; }
    }
#pragma unroll
    for (int i = 0; i < 36; ++i) {
      u64 s0 = __shfl(rBlo, i), s1 = __shfl(rBhi, i);
      if ((k1 >> i) & 1ull) { k0 &= ~s0; k1 &= ~s1; }
    }
    if (lane == 0) { keepm[0] = k0; keepm[1] = k1; }
  }
  __syncthreads();

  if (tid < KTOP) {
    out[tid * 4 + 0] = bx[tid][0];
    out[tid * 4 + 1] = bx[tid][1];
    out[tid * 4 + 2] = bx[tid][2];
    out[tid * 4 + 3] = bx[tid][3];
    out[400 + tid] = sc[tid];
    out[500 + tid] = (float)(sid[tid] % 20u);
    bool kp = (tid < 64) ? ((keepm[0] >> tid) & 1ull)
                         : ((keepm[1] >> (tid - 64)) & 1ull);
    out[600 + tid] = kp ? 1.0f : 0.0f;
  }
}

extern "C" void kernel_launch(void* const* d_in, const int* in_sizes, int n_in,
                              void* d_out, int out_size, void* d_ws, size_t ws_size,
                              hipStream_t stream) {
  (void)in_sizes; (void)n_in; (void)out_size; (void)ws_size;
  const float* obj  = (const float*)d_in[0];
  const float* cls  = (const float*)d_in[1];
  const float* reg  = (const float*)d_in[2];
  const float* anch = (const float*)d_in[3];
  float* out = (float*)d_out;

  u32* meta = (u32*)d_ws;
  u64* cand = (u64*)((char*)d_ws + 64);

  hipMemsetAsync(meta, 0, 64, stream);
  hipLaunchKernelGGL(k_scan, dim3(NB), dim3(256), 0, stream, obj, cls, meta, cand);
  hipLaunchKernelGGL(k_tail, dim3(1),  dim3(256), 0, stream,
                     obj, cls, reg, anch, meta, cand, out);
}